// Round 1
// baseline (237.993 us; speedup 1.0000x reference)
//
#include <hip/hip_runtime.h>

// Problem constants (reference: LEOBlock)
#define FEAT 640
#define LAT 64
#define REL 128      // 2*LAT
#define NWAY 20
#define KSHOT 50     // S / NWAY = 1000/20

// ---------------------------------------------------------------------------
// Kernel 1: class means of support.  cmean[c][f] = mean_k support[c*50+k][f]
// grid = 20 blocks, block = 640 threads; fully coalesced (640 consecutive
// floats per row read per k-step).
// ---------------------------------------------------------------------------
__global__ __launch_bounds__(640) void cmean_kernel(const float* __restrict__ support,
                                                    float* __restrict__ cmean) {
    const int c = blockIdx.x;   // 0..19
    const int f = threadIdx.x;  // 0..639
    const float* p = support + (size_t)(c * KSHOT) * FEAT + f;
    float s = 0.f;
#pragma unroll
    for (int k = 0; k < KSHOT; ++k) s += p[(size_t)k * FEAT];
    cmean[c * FEAT + f] = s * (1.0f / KSHOT);
}

// ---------------------------------------------------------------------------
// Kernel 2 (single block, 1024 threads): everything else.
//   emb[c][l]   = sum_f cmean[c][f] * W_enc[l][f]          (20x64)
//   embbar[l]   = mean_c emb[c][l]
//   cat[c]      = [emb[c], embbar]                          (20x128)
//   v1 = cat@W1.T ; v2 = v1@W2.T ; codes = v2@W3.T          (20x128 each)
//   out[c][k][:] = codes[c]  for k = 0..49                  (20x50x128)
// Weights staged through one padded LDS tile (stride 129 -> (rl+q)%32 banks,
// 2-way = free).  Activation reads are wave-uniform (LDS/global broadcast).
// NOTE: cmean may alias out (fallback path) — all cmean reads complete before
// any out write, separated by __syncthreads, so no __restrict__ on those two.
// ---------------------------------------------------------------------------
__global__ __launch_bounds__(1024) void codes_kernel(const float* cmean,
                                                     const float* __restrict__ W_enc,
                                                     const float* __restrict__ W1,
                                                     const float* __restrict__ W2,
                                                     const float* __restrict__ W3,
                                                     float* out) {
    __shared__ float s_w[64 * 129];       // 33024 B weight tile (padded)
    __shared__ float s_cat[NWAY * REL];   // 10240 B
    __shared__ float s_va[NWAY * REL];    // 10240 B
    __shared__ float s_vb[NWAY * REL];    // 10240 B   (total 63744 B < 64 KiB)

    const int tid = threadIdx.x;

    // ---- encoder: 1280 outputs (o = c*64 + l), f tiled in chunks of 128 ----
    float acc0 = 0.f, acc1 = 0.f;
    for (int ft = 0; ft < FEAT / 128; ++ft) {
        __syncthreads();  // previous tile's consumers done before overwrite
        for (int i = tid; i < 64 * 128; i += 1024) {
            const int l = i >> 7, q = i & 127;
            s_w[l * 129 + q] = W_enc[l * FEAT + ft * 128 + q];  // coalesced
        }
        __syncthreads();
        {
            const int o = tid;                 // wave-uniform c, l = lane
            const int c = o >> 6, l = o & 63;
            const float* cm = cmean + c * FEAT + ft * 128;  // uniform addr -> broadcast
            const float* wr = s_w + l * 129;
#pragma unroll
            for (int q = 0; q < 128; ++q) acc0 += cm[q] * wr[q];
        }
        if (tid < 256) {
            const int o = tid + 1024;
            const int c = o >> 6, l = o & 63;
            const float* cm = cmean + c * FEAT + ft * 128;
            const float* wr = s_w + l * 129;
#pragma unroll
            for (int q = 0; q < 128; ++q) acc1 += cm[q] * wr[q];
        }
    }
    // write emb into left half of cat
    {
        const int o = tid, c = o >> 6, l = o & 63;
        s_cat[c * REL + l] = acc0;
    }
    if (tid < 256) {
        const int o = tid + 1024, c = o >> 6, l = o & 63;
        s_cat[c * REL + l] = acc1;
    }
    __syncthreads();

    // ---- embbar -> right half of every cat row ----
    if (tid < LAT) {
        float s = 0.f;
#pragma unroll
        for (int c = 0; c < NWAY; ++c) s += s_cat[c * REL + tid];
        s *= (1.0f / NWAY);
#pragma unroll
        for (int c = 0; c < NWAY; ++c) s_cat[c * REL + LAT + tid] = s;
    }

    // ---- one bias-free linear stage: s_out[c][r] = sum_q s_in[c][q]*W[r][q] ----
    auto stage = [&](const float* __restrict__ W, const float* s_in, float* s_out) {
        for (int rt = 0; rt < 2; ++rt) {      // 2 tiles of 64 output rows
            __syncthreads();                  // prior consumers of s_w done
            for (int i = tid; i < 64 * 128; i += 1024) {
                const int rl = i >> 7, q = i & 127;
                s_w[rl * 129 + q] = W[(rt * 64 + rl) * REL + q];  // coalesced
            }
            __syncthreads();
            {
                const int o = tid;            // c = o>>6 (wave-uniform), rl = lane
                const int c = o >> 6, rl = o & 63;
                if (c < NWAY) {
                    float acc = 0.f;
#pragma unroll
                    for (int q = 0; q < REL; ++q)
                        acc += s_in[c * REL + q] * s_w[rl * 129 + q];
                    s_out[c * REL + rt * 64 + rl] = acc;
                }
            }
            if (tid < 256) {
                const int o = tid + 1024;
                const int c = o >> 6, rl = o & 63;
                float acc = 0.f;
#pragma unroll
                for (int q = 0; q < REL; ++q)
                    acc += s_in[c * REL + q] * s_w[rl * 129 + q];
                s_out[c * REL + rt * 64 + rl] = acc;
            }
        }
        __syncthreads();
    };

    stage(W1, s_cat, s_va);
    stage(W2, s_va, s_vb);
    stage(W3, s_vb, s_va);   // codes live in s_va

    // ---- broadcast codes[c] over 50 shots: 128000 floats = 32000 float4 ----
    for (int i = tid; i < NWAY * KSHOT * REL / 4; i += 1024) {
        const int idx = i * 4;
        const int c = idx / (KSHOT * REL);
        const int r = idx & (REL - 1);       // float4-aligned (idx multiple of 4)
        const float4 v = *(const float4*)(s_va + c * REL + r);
        *(float4*)(out + idx) = v;           // coalesced 16 B/lane
    }
}

// ---------------------------------------------------------------------------
extern "C" void kernel_launch(void* const* d_in, const int* in_sizes, int n_in,
                              void* d_out, int out_size, void* d_ws, size_t ws_size,
                              hipStream_t stream) {
    const float* support = (const float*)d_in[0];   // [1000][640]
    const float* W_enc   = (const float*)d_in[1];   // [64][640]
    const float* W1      = (const float*)d_in[2];   // [128][128]
    const float* W2      = (const float*)d_in[3];   // [128][128]
    const float* W3      = (const float*)d_in[4];   // [128][128]
    float* out = (float*)d_out;                     // [20][50][128] = 128000

    // scratch for class means (20*640 floats); prefer d_ws, else stash in the
    // front of d_out (safe: codes_kernel reads it fully before overwriting).
    float* cmean = (ws_size >= (size_t)(NWAY * FEAT) * sizeof(float))
                       ? (float*)d_ws : out;

    cmean_kernel<<<NWAY, FEAT, 0, stream>>>(support, cmean);
    codes_kernel<<<1, 1024, 0, stream>>>(cmean, W_enc, W1, W2, W3, out);
}

// Round 2
// 25.827 us; speedup vs baseline: 9.2149x; 9.2149x over previous
//
#include <hip/hip_runtime.h>

// LEOBlock collapsed: codes[c] = [emb(cmean[c]), embbar] @ W1^T @ W2^T @ W3^T,
// broadcast over 50 shots.  All stages parallel over 20 classes.
#define FEAT 640
#define LAT 64
#define REL 128      // 2*LAT
#define NWAY 20
#define KSHOT 50
#define OUT_STRIDE 6400   // KSHOT*REL floats per class in d_out

// per-class scratch layout (floats):
//   [0,640)   cmean
//   [640,704) emb
//   [704,832) v1
//   [832,960) v2
#define WS_STRIDE 960

// ---------------------------------------------------------------------------
// K1: class means. 20 blocks x 640 threads, coalesced (64 consecutive floats
// per wave per row).
// ---------------------------------------------------------------------------
__global__ __launch_bounds__(640) void cmean_kernel(const float* __restrict__ support,
                                                    float* sbase, int sstride) {
    const int c = blockIdx.x, f = threadIdx.x;
    const float* p = support + (size_t)(c * KSHOT) * FEAT + f;
    float s = 0.f;
#pragma unroll
    for (int k = 0; k < KSHOT; ++k) s += p[(size_t)k * FEAT];
    sbase[(size_t)c * sstride + f] = s * (1.0f / KSHOT);
}

// ---------------------------------------------------------------------------
// K2: emb[c][l] = cmean[c] . W_enc[l].  20 blocks x 256 threads:
// 4 threads per output, 40 float4 MACs each, quad shfl reduce.
// ---------------------------------------------------------------------------
__global__ __launch_bounds__(256) void emb_kernel(const float* __restrict__ W_enc,
                                                  float* sbase, int sstride) {
    __shared__ float cm[FEAT];
    const int c = blockIdx.x, t = threadIdx.x;
    const float* cmg = sbase + (size_t)c * sstride;
    for (int i = t; i < FEAT; i += 256) cm[i] = cmg[i];   // coalesced
    __syncthreads();

    const int l = t >> 2, p = t & 3;                      // output row, quad pos
    const float4* wr = (const float4*)(W_enc + l * FEAT + p * 160);
    const float4* xv = (const float4*)(cm + p * 160);
    float a0 = 0.f, a1 = 0.f, a2 = 0.f, a3 = 0.f;
#pragma unroll
    for (int i = 0; i < 40; ++i) {
        const float4 w = wr[i], x = xv[i];
        a0 += w.x * x.x; a1 += w.y * x.y; a2 += w.z * x.z; a3 += w.w * x.w;
    }
    float acc = (a0 + a1) + (a2 + a3);
    acc += __shfl_down(acc, 2, 4);
    acc += __shfl_down(acc, 1, 4);
    if (p == 0) sbase[(size_t)c * sstride + FEAT + l] = acc;
}

// ---------------------------------------------------------------------------
// K3: v1[c] = [emb[c], embbar] @ W1^T.  20 blocks x 128 threads.
// embbar recomputed per block (20x64 reads, cheap, avoids an extra kernel).
// ---------------------------------------------------------------------------
__global__ __launch_bounds__(128) void rel1_kernel(const float* __restrict__ W1,
                                                   float* sbase, int sstride) {
    __shared__ float s_in[REL];
    const int c = blockIdx.x, t = threadIdx.x;
    if (t < LAT) {
        s_in[t] = sbase[(size_t)c * sstride + FEAT + t];
    } else {
        const int l = t - LAT;
        float s = 0.f;
#pragma unroll
        for (int cc = 0; cc < NWAY; ++cc) s += sbase[(size_t)cc * sstride + FEAT + l];
        s_in[LAT + l] = s * (1.0f / NWAY);
    }
    __syncthreads();
    const float4* wr = (const float4*)(W1 + t * REL);
    const float4* xv = (const float4*)s_in;
    float a0 = 0.f, a1 = 0.f, a2 = 0.f, a3 = 0.f;
#pragma unroll
    for (int i = 0; i < 32; ++i) {
        const float4 w = wr[i], x = xv[i];
        a0 += w.x * x.x; a1 += w.y * x.y; a2 += w.z * x.z; a3 += w.w * x.w;
    }
    sbase[(size_t)c * sstride + FEAT + LAT + t] = (a0 + a1) + (a2 + a3);
}

// ---------------------------------------------------------------------------
// K4: v2[c] = v1[c] @ W2^T.  20 blocks x 128 threads.
// ---------------------------------------------------------------------------
__global__ __launch_bounds__(128) void rel2_kernel(const float* __restrict__ W2,
                                                   float* sbase, int sstride) {
    __shared__ float s_in[REL];
    const int c = blockIdx.x, t = threadIdx.x;
    s_in[t] = sbase[(size_t)c * sstride + FEAT + LAT + t];   // coalesced
    __syncthreads();
    const float4* wr = (const float4*)(W2 + t * REL);
    const float4* xv = (const float4*)s_in;
    float a0 = 0.f, a1 = 0.f, a2 = 0.f, a3 = 0.f;
#pragma unroll
    for (int i = 0; i < 32; ++i) {
        const float4 w = wr[i], x = xv[i];
        a0 += w.x * x.x; a1 += w.y * x.y; a2 += w.z * x.z; a3 += w.w * x.w;
    }
    sbase[(size_t)c * sstride + FEAT + LAT + REL + t] = (a0 + a1) + (a2 + a3);
}

// ---------------------------------------------------------------------------
// K5: codes[c] = v2[c] @ W3^T, broadcast over 50 shots into d_out.
// In the no-ws fallback sbase aliases out: block c reads only its OWN slice
// (staged to LDS, __syncthreads drains loads) before overwriting it.
// ---------------------------------------------------------------------------
__global__ __launch_bounds__(128) void rel3_kernel(const float* __restrict__ W3,
                                                   const float* sbase, int sstride,
                                                   float* out) {
    __shared__ float s_in[REL];
    const int c = blockIdx.x, t = threadIdx.x;
    s_in[t] = sbase[(size_t)c * sstride + FEAT + LAT + REL + t];
    __syncthreads();
    const float4* wr = (const float4*)(W3 + t * REL);
    const float4* xv = (const float4*)s_in;
    float a0 = 0.f, a1 = 0.f, a2 = 0.f, a3 = 0.f;
#pragma unroll
    for (int i = 0; i < 32; ++i) {
        const float4 w = wr[i], x = xv[i];
        a0 += w.x * x.x; a1 += w.y * x.y; a2 += w.z * x.z; a3 += w.w * x.w;
    }
    const float acc = (a0 + a1) + (a2 + a3);
    float* o = out + (size_t)c * OUT_STRIDE + t;
#pragma unroll
    for (int k = 0; k < KSHOT; ++k) o[(size_t)k * REL] = acc;   // coalesced per k
}

// ---------------------------------------------------------------------------
extern "C" void kernel_launch(void* const* d_in, const int* in_sizes, int n_in,
                              void* d_out, int out_size, void* d_ws, size_t ws_size,
                              hipStream_t stream) {
    const float* support = (const float*)d_in[0];   // [1000][640]
    const float* W_enc   = (const float*)d_in[1];   // [64][640]
    const float* W1      = (const float*)d_in[2];   // [128][128]
    const float* W2      = (const float*)d_in[3];   // [128][128]
    const float* W3      = (const float*)d_in[4];   // [128][128]
    float* out = (float*)d_out;                     // [20][50][128]

    float* sbase;
    int sstride;
    if (ws_size >= (size_t)NWAY * WS_STRIDE * sizeof(float)) {
        sbase = (float*)d_ws;  sstride = WS_STRIDE;
    } else {
        // fallback: stash per-class scratch inside each class's own out-slice;
        // rel3 reads its own slice before fully overwriting it.
        sbase = out;           sstride = OUT_STRIDE;
    }

    cmean_kernel<<<NWAY, 640, 0, stream>>>(support, sbase, sstride);
    emb_kernel  <<<NWAY, 256, 0, stream>>>(W_enc, sbase, sstride);
    rel1_kernel <<<NWAY, 128, 0, stream>>>(W1, sbase, sstride);
    rel2_kernel <<<NWAY, 128, 0, stream>>>(W2, sbase, sstride);
    rel3_kernel <<<NWAY, 128, 0, stream>>>(W3, sbase, sstride, out);
}